// Round 2
// baseline (601.392 us; speedup 1.0000x reference)
//
#include <hip/hip_runtime.h>

#define IN_DIM 128
#define OUT_DIM 64
#define ALPHA 0.2f
#define R_BLK 64   // rows staged in LDS per tile (32 KB)

// ---------------------------------------------------------------------------
// Kernel 1: M_b = P_b @ W_slice_b, three [128][64] matrices into d_ws.
//   M0 = P_company @ W_PCC[  0: 64]
//   M1 = P_company @ W_PCC[ 64:128]
//   M2 = P_person  @ W_PCC[128:192]
// ---------------------------------------------------------------------------
__global__ __launch_bounds__(256) void compute_M_kernel(
    const float* __restrict__ P_company,
    const float* __restrict__ P_person,
    const float* __restrict__ W_PCC,
    float* __restrict__ M)
{
    const int mb = blockIdx.x >> 4;     // which matrix (0,1,2)
    const int chunk = blockIdx.x & 15;  // which 512-entry chunk of 8192
    const float* __restrict__ P = (mb == 2) ? P_person : P_company;
    const float* __restrict__ Wb = W_PCC + mb * OUT_DIM * OUT_DIM;
    float* __restrict__ Mb = M + mb * IN_DIM * OUT_DIM;
    const int base = chunk * 512;
    for (int idx = base + threadIdx.x; idx < base + 512; idx += 256) {
        const int r = idx >> 6;
        const int c = idx & 63;
        float acc = 0.f;
#pragma unroll
        for (int k = 0; k < OUT_DIM; ++k)
            acc = fmaf(P[r * OUT_DIM + k], Wb[k * OUT_DIM + c], acc);
        Mb[idx] = acc;
    }
}

// ---------------------------------------------------------------------------
// Kernel 2: table GEMM  out[t] = feats @ M[t]   ([nrows,128] @ [128,64]).
// lane = output column. Each wave keeps its M column-slice in 128 VGPRs
// (loaded once). X tile staged in LDS (coalesced), inner-loop reads are
// wave-uniform broadcasts. NT=2: waves 0/2 -> table0, waves 1/3 -> table1,
// sharing one read of feats.
// ---------------------------------------------------------------------------
template <int NT>
__global__ __launch_bounds__(256) void table_kernel(
    const float* __restrict__ feats, int nrows,
    const float* __restrict__ Mg,   // NT matrices [128][64] contiguous
    float* __restrict__ out)        // NT tables [nrows][64] contiguous
{
    __shared__ float xs[R_BLK][IN_DIM];  // 32 KB
    const int w = threadIdx.x >> 6;
    const int lane = threadIdx.x & 63;
    const int table = (NT == 2) ? (w & 1) : 0;
    const int seg   = (NT == 2) ? (w >> 1) : w;
    const int SEGS  = 4 / NT;            // row segments per tile
    const int RW    = R_BLK / SEGS;      // rows per wave per tile

    // M column-slice for this wave's table: 128 VGPRs, loaded once.
    float Mreg[IN_DIM];
    const float* __restrict__ Mt = Mg + table * IN_DIM * OUT_DIM;
#pragma unroll
    for (int k = 0; k < IN_DIM; ++k)
        Mreg[k] = Mt[k * OUT_DIM + lane];

    float* __restrict__ outT = out + (size_t)table * nrows * OUT_DIM;

    const int ntiles = (nrows + R_BLK - 1) / R_BLK;
    for (int tile = blockIdx.x; tile < ntiles; tile += gridDim.x) {
        const long long row0 = (long long)tile * R_BLK;
        __syncthreads();  // protect previous tile's reads
        // cooperative coalesced stage: R_BLK*IN_DIM floats = 2048 float4
        for (int i = threadIdx.x; i < R_BLK * (IN_DIM / 4); i += 256) {
            const int r = i / (IN_DIM / 4);
            const int c = i % (IN_DIM / 4);
            const long long gr = row0 + r;
            float4 v = (gr < nrows) ? ((const float4*)(feats + gr * IN_DIM))[c]
                                    : make_float4(0.f, 0.f, 0.f, 0.f);
            ((float4*)xs[r])[c] = v;
        }
        __syncthreads();
        // compute: rows in pairs for ILP (4 independent FMA chains)
        for (int rr = 0; rr < RW; rr += 2) {
            const int r0 = seg * RW + rr;
            const int r1 = r0 + 1;
            float a0 = 0.f, b0 = 0.f, a1 = 0.f, b1 = 0.f;
#pragma unroll
            for (int k4 = 0; k4 < IN_DIM / 4; ++k4) {
                const float4 x0 = ((const float4*)xs[r0])[k4];  // broadcast
                const float4 x1 = ((const float4*)xs[r1])[k4];  // broadcast
                a0 = fmaf(x0.x, Mreg[4 * k4 + 0], a0);
                b0 = fmaf(x0.y, Mreg[4 * k4 + 1], b0);
                a0 = fmaf(x0.z, Mreg[4 * k4 + 2], a0);
                b0 = fmaf(x0.w, Mreg[4 * k4 + 3], b0);
                a1 = fmaf(x1.x, Mreg[4 * k4 + 0], a1);
                b1 = fmaf(x1.y, Mreg[4 * k4 + 1], b1);
                a1 = fmaf(x1.z, Mreg[4 * k4 + 2], a1);
                b1 = fmaf(x1.w, Mreg[4 * k4 + 3], b1);
            }
            const long long gr0 = row0 + r0;
            const long long gr1 = row0 + r1;
            if (gr0 < nrows) outT[gr0 * OUT_DIM + lane] = a0 + b0;
            if (gr1 < nrows) outT[gr1 * OUT_DIM + lane] = a1 + b1;
        }
    }
}

// ---------------------------------------------------------------------------
// Kernel 3: gather + add + LeakyReLU.
// 16 threads per edge, float4 per thread -> fully coalesced 256B per edge.
// ---------------------------------------------------------------------------
__global__ __launch_bounds__(256) void gather_kernel(
    const int* __restrict__ i0, const int* __restrict__ i1, const int* __restrict__ i2,
    const float* __restrict__ g0, const float* __restrict__ g1, const float* __restrict__ g2,
    float* __restrict__ out, long long E)
{
    const long long t = (long long)blockIdx.x * 256 + threadIdx.x;
    const long long e = t >> 4;
    if (e >= E) return;
    const int sub = ((int)t & 15) << 2;
    const long long r0 = i0[e];
    const long long r1 = i1[e];
    const long long r2 = i2[e];
    const float4 a = *(const float4*)(g0 + r0 * OUT_DIM + sub);
    const float4 b = *(const float4*)(g1 + r1 * OUT_DIM + sub);
    const float4 c = *(const float4*)(g2 + r2 * OUT_DIM + sub);
    float4 p;
    p.x = a.x + b.x + c.x;
    p.y = a.y + b.y + c.y;
    p.z = a.z + b.z + c.z;
    p.w = a.w + b.w + c.w;
    p.x = p.x >= 0.f ? p.x : ALPHA * p.x;
    p.y = p.y >= 0.f ? p.y : ALPHA * p.y;
    p.z = p.z >= 0.f ? p.z : ALPHA * p.z;
    p.w = p.w >= 0.f ? p.w : ALPHA * p.w;
    *(float4*)(out + e * OUT_DIM + sub) = p;
}

// ---------------------------------------------------------------------------
// Fallback (only if ws too small for tables): direct per-edge compute.
// ---------------------------------------------------------------------------
__global__ __launch_bounds__(256) void fused_fallback_kernel(
    const float* __restrict__ T, const float* __restrict__ Pp,
    const int* __restrict__ i0, const int* __restrict__ i1, const int* __restrict__ i2,
    const float* __restrict__ M, float* __restrict__ out, long long E)
{
    const int wave = threadIdx.x >> 6;
    const int lane = threadIdx.x & 63;
    const long long wavesTotal = (long long)gridDim.x * 4;
    const float* __restrict__ M0 = M;
    const float* __restrict__ M1 = M + IN_DIM * OUT_DIM;
    const float* __restrict__ M2 = M + 2 * IN_DIM * OUT_DIM;
    for (long long e = (long long)blockIdx.x * 4 + wave; e < E; e += wavesTotal) {
        const float* __restrict__ x0 = T + (long long)i0[e] * IN_DIM;
        const float* __restrict__ x1 = T + (long long)i1[e] * IN_DIM;
        const float* __restrict__ x2 = Pp + (long long)i2[e] * IN_DIM;
        float acc = 0.f;
#pragma unroll 4
        for (int k = 0; k < IN_DIM; ++k) {
            acc = fmaf(x0[k], M0[k * OUT_DIM + lane], acc);
            acc = fmaf(x1[k], M1[k * OUT_DIM + lane], acc);
            acc = fmaf(x2[k], M2[k * OUT_DIM + lane], acc);
        }
        acc = acc >= 0.f ? acc : ALPHA * acc;
        out[e * OUT_DIM + lane] = acc;
    }
}

// ---------------------------------------------------------------------------
extern "C" void kernel_launch(void* const* d_in, const int* in_sizes, int n_in,
                              void* d_out, int out_size, void* d_ws, size_t ws_size,
                              hipStream_t stream) {
    const float* T    = (const float*)d_in[0];  // taxPayer_feats [N_C,128]
    const float* Pp   = (const float*)d_in[1];  // person_feats   [N_P,128]
    // d_in[2] item_feats: unused for PCC
    const int*   i0   = (const int*)d_in[3];
    const int*   i1   = (const int*)d_in[4];
    const int*   i2   = (const int*)d_in[5];
    const float* Pc   = (const float*)d_in[6];  // P_company [128,64]
    const float* Pper = (const float*)d_in[7];  // P_person  [128,64]
    const float* W    = (const float*)d_in[9];  // W_PCC     [192,64]
    float* out = (float*)d_out;

    const int n_c = in_sizes[0] / IN_DIM;
    const int n_p = in_sizes[1] / IN_DIM;
    const long long E = in_sizes[3];

    float* M = (float*)d_ws;
    const size_t needM = (size_t)3 * IN_DIM * OUT_DIM * sizeof(float);
    const size_t tblBytes = ((size_t)n_c * 2 + (size_t)n_p) * OUT_DIM * sizeof(float);

    // 1) fused projection matrices
    compute_M_kernel<<<48, 256, 0, stream>>>(Pc, Pper, W, M);

    if (ws_size >= needM + tblBytes) {
        float* g0 = M + 3 * IN_DIM * OUT_DIM;   // [n_c][64] then [n_c][64] then [n_p][64]
        float* g2 = g0 + (size_t)2 * n_c * OUT_DIM;

        // 2) tables: g0/g1 from taxPayer (one read of T), g2 from person
        {
            const int ntiles = (n_c + R_BLK - 1) / R_BLK;
            const int grid = ntiles < 1536 ? ntiles : 1536;
            table_kernel<2><<<grid, 256, 0, stream>>>(T, n_c, M, g0);
        }
        {
            const int ntiles = (n_p + R_BLK - 1) / R_BLK;
            const int grid = ntiles < 1536 ? ntiles : 1536;
            table_kernel<1><<<grid, 256, 0, stream>>>(Pp, n_p, M + 2 * IN_DIM * OUT_DIM, g2);
        }

        // 3) gather + add + LeakyReLU
        const float* g1 = g0 + (size_t)n_c * OUT_DIM;
        const long long threads = E * 16;
        gather_kernel<<<(int)((threads + 255) / 256), 256, 0, stream>>>(
            i0, i1, i2, g0, g1, g2, out, E);
    } else {
        fused_fallback_kernel<<<16384, 256, 0, stream>>>(T, Pp, i0, i1, i2, M, out, E);
    }
}

// Round 3
// 244.678 us; speedup vs baseline: 2.4579x; 2.4579x over previous
//
#include <hip/hip_runtime.h>

#define IN_DIM 128
#define OUT_DIM 64
#define ALPHA 0.2f

typedef __attribute__((ext_vector_type(8))) short short8v;  // 8 bf16 (4 VGPRs)
typedef __attribute__((ext_vector_type(4))) float f32x4;    // MFMA acc

__device__ __forceinline__ unsigned short bf16rne(float x) {
    union { float f; unsigned u; } c; c.f = x;
    const unsigned u = c.u;
    return (unsigned short)((u + 0x7fffu + ((u >> 16) & 1u)) >> 16);
}

// ---------------------------------------------------------------------------
// Kernel 1: M_b = P_b @ W_slice_b -> f32 M[3][128][64] and bf16 Mt[3][64][128]
//   M0 = P_company @ W_PCC[  0: 64]
//   M1 = P_company @ W_PCC[ 64:128]
//   M2 = P_person  @ W_PCC[128:192]
// ---------------------------------------------------------------------------
__global__ __launch_bounds__(256) void compute_M_kernel(
    const float* __restrict__ P_company,
    const float* __restrict__ P_person,
    const float* __restrict__ W_PCC,
    float* __restrict__ M,              // [3][128][64] f32
    unsigned short* __restrict__ Mt)    // [3][64][128] bf16 (transposed)
{
    const int mb = blockIdx.x >> 4;     // which matrix (0,1,2)
    const int chunk = blockIdx.x & 15;  // which 512-entry chunk of 8192
    const float* __restrict__ P = (mb == 2) ? P_person : P_company;
    const float* __restrict__ Wb = W_PCC + mb * OUT_DIM * OUT_DIM;
    float* __restrict__ Mb = M + mb * IN_DIM * OUT_DIM;
    const int base = chunk * 512;
    for (int idx = base + threadIdx.x; idx < base + 512; idx += 256) {
        const int r = idx >> 6;   // k index 0..127
        const int c = idx & 63;   // col 0..63
        float acc = 0.f;
#pragma unroll
        for (int k = 0; k < OUT_DIM; ++k)
            acc = fmaf(P[r * OUT_DIM + k], Wb[k * OUT_DIM + c], acc);
        Mb[idx] = acc;
        Mt[(mb * OUT_DIM + c) * IN_DIM + r] = bf16rne(acc);
    }
}

// ---------------------------------------------------------------------------
// Kernel 2: table GEMM via MFMA.  out[t] = feats @ M[t]  ([nrows,128]@[128,64])
// One wave per 16-row tile (grid-stride). B-fragments (whole M, bf16) live in
// VGPRs, preloaded once per wave from Mt. A loaded f32 from global (2 float4
// per K=32 chunk, row fully consumed), converted to bf16 in-register.
// Fragment maps (16x16x32 bf16):
//   a[4h+j] = A[l&15][k0 + 16h + (l>>4)*4 + j]
//   b[4h+j] = M[k0 + 16h + (l>>4)*4 + j][c0 + (l&15)]
//   D[(l>>4)*4 + j][c0 + (l&15)] = acc[j]
// ---------------------------------------------------------------------------
template <int NT>
__global__ __launch_bounds__(256) void table_mfma_kernel(
    const float* __restrict__ feats, int nrows,
    const unsigned short* __restrict__ Mt,  // NT matrices [64][128] bf16
    float* __restrict__ out)                // NT tables [nrows][64] f32
{
    const int w    = threadIdx.x >> 6;
    const int lane = threadIdx.x & 63;
    const int fr   = lane & 15;   // A-row / B,D-col index
    const int fq   = lane >> 4;   // k-subgroup / D-row-group

    // ---- preload all B fragments: NT x 4(k0) x 4(c0) x 8 bf16 ----
    union FragU { short8v v; uint2 q[2]; };
    short8v bfrag[NT][4][4];
#pragma unroll
    for (int t = 0; t < NT; ++t)
#pragma unroll
        for (int k0i = 0; k0i < 4; ++k0i)
#pragma unroll
            for (int c0i = 0; c0i < 4; ++c0i) {
                const unsigned short* p =
                    Mt + ((size_t)(t * OUT_DIM + c0i * 16 + fr)) * IN_DIM + k0i * 32 + fq * 4;
                FragU f;
                f.q[0] = *(const uint2*)(p);        // k offset +0..+3
                f.q[1] = *(const uint2*)(p + 16);   // k offset +16..+19
                bfrag[t][k0i][c0i] = f.v;
            }

    const int ntiles  = (nrows + 15) >> 4;
    const int wstride = gridDim.x * 4;
    union F4 { float4 v; float f[4]; };
    union AF { short8v v; unsigned short u[8]; };

    for (int tile = blockIdx.x * 4 + w; tile < ntiles; tile += wstride) {
        const long long row0 = (long long)tile * 16;
        long long ar = row0 + fr;
        if (ar >= nrows) ar = nrows - 1;
        const float* __restrict__ A = feats + ar * IN_DIM;

        // A tile: 8 float4 loads (each wave reads 16 rows x 64B per inst)
        F4 L[8];
#pragma unroll
        for (int k0i = 0; k0i < 4; ++k0i) {
            L[k0i * 2 + 0].v = *(const float4*)(A + k0i * 32 + fq * 4);
            L[k0i * 2 + 1].v = *(const float4*)(A + k0i * 32 + 16 + fq * 4);
        }
        // convert to bf16 A-fragments
        short8v afrag[4];
#pragma unroll
        for (int k0i = 0; k0i < 4; ++k0i) {
            AF af;
#pragma unroll
            for (int j = 0; j < 4; ++j) {
                af.u[j]     = bf16rne(L[k0i * 2 + 0].f[j]);
                af.u[4 + j] = bf16rne(L[k0i * 2 + 1].f[j]);
            }
            afrag[k0i] = af.v;
        }

        f32x4 acc[NT][4];
#pragma unroll
        for (int t = 0; t < NT; ++t)
#pragma unroll
            for (int c0i = 0; c0i < 4; ++c0i)
                acc[t][c0i] = (f32x4){0.f, 0.f, 0.f, 0.f};

#pragma unroll
        for (int k0i = 0; k0i < 4; ++k0i)
#pragma unroll
            for (int c0i = 0; c0i < 4; ++c0i)
#pragma unroll
                for (int t = 0; t < NT; ++t)
                    acc[t][c0i] = __builtin_amdgcn_mfma_f32_16x16x32_bf16(
                        afrag[k0i], bfrag[t][k0i][c0i], acc[t][c0i], 0, 0, 0);

        // store: D[(fq*4+j)][c0+fr]
#pragma unroll
        for (int t = 0; t < NT; ++t) {
            float* __restrict__ op = out + (size_t)t * nrows * OUT_DIM;
#pragma unroll
            for (int c0i = 0; c0i < 4; ++c0i)
#pragma unroll
                for (int j = 0; j < 4; ++j) {
                    const long long rg = row0 + fq * 4 + j;
                    if (rg < nrows)
                        op[rg * OUT_DIM + c0i * 16 + fr] = acc[t][c0i][j];
                }
        }
    }
}

// ---------------------------------------------------------------------------
// Kernel 3: gather + add + LeakyReLU.
// 16 threads per edge, float4 per thread -> fully coalesced 256B per edge.
// ---------------------------------------------------------------------------
__global__ __launch_bounds__(256) void gather_kernel(
    const int* __restrict__ i0, const int* __restrict__ i1, const int* __restrict__ i2,
    const float* __restrict__ g0, const float* __restrict__ g1, const float* __restrict__ g2,
    float* __restrict__ out, long long E)
{
    const long long t = (long long)blockIdx.x * 256 + threadIdx.x;
    const long long e = t >> 4;
    if (e >= E) return;
    const int sub = ((int)t & 15) << 2;
    const long long r0 = i0[e];
    const long long r1 = i1[e];
    const long long r2 = i2[e];
    const float4 a = *(const float4*)(g0 + r0 * OUT_DIM + sub);
    const float4 b = *(const float4*)(g1 + r1 * OUT_DIM + sub);
    const float4 c = *(const float4*)(g2 + r2 * OUT_DIM + sub);
    float4 p;
    p.x = a.x + b.x + c.x;
    p.y = a.y + b.y + c.y;
    p.z = a.z + b.z + c.z;
    p.w = a.w + b.w + c.w;
    p.x = p.x >= 0.f ? p.x : ALPHA * p.x;
    p.y = p.y >= 0.f ? p.y : ALPHA * p.y;
    p.z = p.z >= 0.f ? p.z : ALPHA * p.z;
    p.w = p.w >= 0.f ? p.w : ALPHA * p.w;
    *(float4*)(out + e * OUT_DIM + sub) = p;
}

// ---------------------------------------------------------------------------
// Fallback (only if ws too small for tables): direct per-edge compute.
// ---------------------------------------------------------------------------
__global__ __launch_bounds__(256) void fused_fallback_kernel(
    const float* __restrict__ T, const float* __restrict__ Pp,
    const int* __restrict__ i0, const int* __restrict__ i1, const int* __restrict__ i2,
    const float* __restrict__ M, float* __restrict__ out, long long E)
{
    const int wave = threadIdx.x >> 6;
    const int lane = threadIdx.x & 63;
    const long long wavesTotal = (long long)gridDim.x * 4;
    const float* __restrict__ M0 = M;
    const float* __restrict__ M1 = M + IN_DIM * OUT_DIM;
    const float* __restrict__ M2 = M + 2 * IN_DIM * OUT_DIM;
    for (long long e = (long long)blockIdx.x * 4 + wave; e < E; e += wavesTotal) {
        const float* __restrict__ x0 = T + (long long)i0[e] * IN_DIM;
        const float* __restrict__ x1 = T + (long long)i1[e] * IN_DIM;
        const float* __restrict__ x2 = Pp + (long long)i2[e] * IN_DIM;
        float acc = 0.f;
#pragma unroll 4
        for (int k = 0; k < IN_DIM; ++k) {
            acc = fmaf(x0[k], M0[k * OUT_DIM + lane], acc);
            acc = fmaf(x1[k], M1[k * OUT_DIM + lane], acc);
            acc = fmaf(x2[k], M2[k * OUT_DIM + lane], acc);
        }
        acc = acc >= 0.f ? acc : ALPHA * acc;
        out[e * OUT_DIM + lane] = acc;
    }
}

// ---------------------------------------------------------------------------
extern "C" void kernel_launch(void* const* d_in, const int* in_sizes, int n_in,
                              void* d_out, int out_size, void* d_ws, size_t ws_size,
                              hipStream_t stream) {
    const float* T    = (const float*)d_in[0];  // taxPayer_feats [N_C,128]
    const float* Pp   = (const float*)d_in[1];  // person_feats   [N_P,128]
    // d_in[2] item_feats: unused for PCC
    const int*   i0   = (const int*)d_in[3];
    const int*   i1   = (const int*)d_in[4];
    const int*   i2   = (const int*)d_in[5];
    const float* Pc   = (const float*)d_in[6];  // P_company [128,64]
    const float* Pper = (const float*)d_in[7];  // P_person  [128,64]
    const float* W    = (const float*)d_in[9];  // W_PCC     [192,64]
    float* out = (float*)d_out;

    const int n_c = in_sizes[0] / IN_DIM;
    const int n_p = in_sizes[1] / IN_DIM;
    const long long E = in_sizes[3];

    // ws layout: [M f32 3*128*64][Mt bf16 3*64*128][tables]
    float* M = (float*)d_ws;
    unsigned short* Mt = (unsigned short*)((char*)d_ws + 98304);
    const size_t tblOff = 98304 + 49152;  // 147456, 16B aligned
    const size_t tblBytes = ((size_t)n_c * 2 + (size_t)n_p) * OUT_DIM * sizeof(float);

    // 1) fused projection matrices (f32 + transposed bf16)
    compute_M_kernel<<<48, 256, 0, stream>>>(Pc, Pper, W, M, Mt);

    if (ws_size >= tblOff + tblBytes) {
        float* g0 = (float*)((char*)d_ws + tblOff);       // [n_c][64]
        float* g1 = g0 + (size_t)n_c * OUT_DIM;           // [n_c][64]
        float* g2 = g1 + (size_t)n_c * OUT_DIM;           // [n_p][64]

        // 2) tables via MFMA: g0/g1 from taxPayer (one read of T), g2 from person
        table_mfma_kernel<2><<<512, 256, 0, stream>>>(T, n_c, Mt, g0);
        table_mfma_kernel<1><<<512, 256, 0, stream>>>(
            Pp, n_p, Mt + (size_t)2 * OUT_DIM * IN_DIM, g2);

        // 3) gather + add + LeakyReLU
        const long long threads = E * 16;
        gather_kernel<<<(int)((threads + 255) / 256), 256, 0, stream>>>(
            i0, i1, i2, g0, g1, g2, out, E);
    } else {
        fused_fallback_kernel<<<16384, 256, 0, stream>>>(T, Pp, i0, i1, i2, M, out, E);
    }
}

// Round 4
// 192.825 us; speedup vs baseline: 3.1188x; 1.2689x over previous
//
#include <hip/hip_runtime.h>

#define IN_DIM 128
#define OUT_DIM 64
#define ALPHA 0.2f

typedef __attribute__((ext_vector_type(8))) short short8v;  // 8 bf16 (4 VGPRs)
typedef __attribute__((ext_vector_type(4))) float f32x4;    // MFMA acc

__device__ __forceinline__ unsigned short bf16rne(float x) {
    union { float f; unsigned u; } c; c.f = x;
    const unsigned u = c.u;
    return (unsigned short)((u + 0x7fffu + ((u >> 16) & 1u)) >> 16);
}

__device__ __forceinline__ float4 bf4_to_f4(uint2 v) {
    float4 r;
    r.x = __uint_as_float(v.x << 16);
    r.y = __uint_as_float(v.x & 0xffff0000u);
    r.z = __uint_as_float(v.y << 16);
    r.w = __uint_as_float(v.y & 0xffff0000u);
    return r;
}

// ---------------------------------------------------------------------------
// Kernel 1: M_b = P_b @ W_slice_b -> f32 M[3][128][64] and bf16 Mt[3][64][128]
//   M0 = P_company @ W_PCC[  0: 64]
//   M1 = P_company @ W_PCC[ 64:128]
//   M2 = P_person  @ W_PCC[128:192]
// ---------------------------------------------------------------------------
__global__ __launch_bounds__(256) void compute_M_kernel(
    const float* __restrict__ P_company,
    const float* __restrict__ P_person,
    const float* __restrict__ W_PCC,
    float* __restrict__ M,              // [3][128][64] f32 (fallback path)
    unsigned short* __restrict__ Mt)    // [3][64][128] bf16 (transposed)
{
    const int mb = blockIdx.x >> 4;     // which matrix (0,1,2)
    const int chunk = blockIdx.x & 15;  // which 512-entry chunk of 8192
    const float* __restrict__ P = (mb == 2) ? P_person : P_company;
    const float* __restrict__ Wb = W_PCC + mb * OUT_DIM * OUT_DIM;
    float* __restrict__ Mb = M + mb * IN_DIM * OUT_DIM;
    const int base = chunk * 512;
    for (int idx = base + threadIdx.x; idx < base + 512; idx += 256) {
        const int r = idx >> 6;   // k index 0..127
        const int c = idx & 63;   // col 0..63
        float acc = 0.f;
#pragma unroll
        for (int k = 0; k < OUT_DIM; ++k)
            acc = fmaf(P[r * OUT_DIM + k], Wb[k * OUT_DIM + c], acc);
        Mb[idx] = acc;
        Mt[(mb * OUT_DIM + c) * IN_DIM + r] = bf16rne(acc);
    }
}

// ---------------------------------------------------------------------------
// Kernel 2: table GEMM via MFMA.  out[t] = feats @ M[t]  ([nrows,128]@[128,64])
// One wave per 16-row tile (grid-stride). B-fragments (whole M, bf16) live in
// VGPRs, preloaded once per wave from Mt. A loaded f32 from global, converted
// to bf16 in-register. Output stored as bf16 tables.
// Fragment maps (16x16x32 bf16):
//   a[4h+j] = A[l&15][k0 + 16h + (l>>4)*4 + j]
//   b[4h+j] = M[k0 + 16h + (l>>4)*4 + j][c0 + (l&15)]
//   D[(l>>4)*4 + j][c0 + (l&15)] = acc[j]
// ---------------------------------------------------------------------------
template <int NT>
__global__ __launch_bounds__(256) void table_mfma_kernel(
    const float* __restrict__ feats, int nrows,
    const unsigned short* __restrict__ Mt,  // NT matrices [64][128] bf16
    unsigned short* __restrict__ out)       // NT tables [nrows][64] bf16
{
    const int w    = threadIdx.x >> 6;
    const int lane = threadIdx.x & 63;
    const int fr   = lane & 15;   // A-row / B,D-col index
    const int fq   = lane >> 4;   // k-subgroup / D-row-group

    // ---- preload all B fragments: NT x 4(k0) x 4(c0) x 8 bf16 ----
    union FragU { short8v v; uint2 q[2]; };
    short8v bfrag[NT][4][4];
#pragma unroll
    for (int t = 0; t < NT; ++t)
#pragma unroll
        for (int k0i = 0; k0i < 4; ++k0i)
#pragma unroll
            for (int c0i = 0; c0i < 4; ++c0i) {
                const unsigned short* p =
                    Mt + ((size_t)(t * OUT_DIM + c0i * 16 + fr)) * IN_DIM + k0i * 32 + fq * 4;
                FragU f;
                f.q[0] = *(const uint2*)(p);        // k offset +0..+3
                f.q[1] = *(const uint2*)(p + 16);   // k offset +16..+19
                bfrag[t][k0i][c0i] = f.v;
            }

    const int ntiles  = (nrows + 15) >> 4;
    const int wstride = gridDim.x * 4;
    union F4 { float4 v; float f[4]; };
    union AF { short8v v; unsigned short u[8]; };

    for (int tile = blockIdx.x * 4 + w; tile < ntiles; tile += wstride) {
        const long long row0 = (long long)tile * 16;
        long long ar = row0 + fr;
        if (ar >= nrows) ar = nrows - 1;
        const float* __restrict__ A = feats + ar * IN_DIM;

        // A tile: 8 float4 loads (each wave reads 16 rows x 64B per inst)
        F4 L[8];
#pragma unroll
        for (int k0i = 0; k0i < 4; ++k0i) {
            L[k0i * 2 + 0].v = *(const float4*)(A + k0i * 32 + fq * 4);
            L[k0i * 2 + 1].v = *(const float4*)(A + k0i * 32 + 16 + fq * 4);
        }
        // convert to bf16 A-fragments
        short8v afrag[4];
#pragma unroll
        for (int k0i = 0; k0i < 4; ++k0i) {
            AF af;
#pragma unroll
            for (int j = 0; j < 4; ++j) {
                af.u[j]     = bf16rne(L[k0i * 2 + 0].f[j]);
                af.u[4 + j] = bf16rne(L[k0i * 2 + 1].f[j]);
            }
            afrag[k0i] = af.v;
        }

        f32x4 acc[NT][4];
#pragma unroll
        for (int t = 0; t < NT; ++t)
#pragma unroll
            for (int c0i = 0; c0i < 4; ++c0i)
                acc[t][c0i] = (f32x4){0.f, 0.f, 0.f, 0.f};

#pragma unroll
        for (int k0i = 0; k0i < 4; ++k0i)
#pragma unroll
            for (int c0i = 0; c0i < 4; ++c0i)
#pragma unroll
                for (int t = 0; t < NT; ++t)
                    acc[t][c0i] = __builtin_amdgcn_mfma_f32_16x16x32_bf16(
                        afrag[k0i], bfrag[t][k0i][c0i], acc[t][c0i], 0, 0, 0);

        // store bf16: D[(fq*4+j)][c0+fr]
#pragma unroll
        for (int t = 0; t < NT; ++t) {
            unsigned short* __restrict__ op = out + (size_t)t * nrows * OUT_DIM;
#pragma unroll
            for (int c0i = 0; c0i < 4; ++c0i)
#pragma unroll
                for (int j = 0; j < 4; ++j) {
                    const long long rg = row0 + fq * 4 + j;
                    if (rg < nrows)
                        op[rg * OUT_DIM + c0i * 16 + fr] = bf16rne(acc[t][c0i][j]);
                }
        }
    }
}

// ---------------------------------------------------------------------------
// Kernel 3: gather + add + LeakyReLU.  Tables are bf16 [nrows][64].
// 16 threads per edge, 2 edges per thread (doubled MLP).
// Per edge: 16 lanes x uint2 (4 bf16 = 8B) consumes the full 128B row.
// Output: float4 per lane per edge -> fully coalesced 256B per edge.
// ---------------------------------------------------------------------------
__global__ __launch_bounds__(256) void gather_kernel(
    const int* __restrict__ i0, const int* __restrict__ i1, const int* __restrict__ i2,
    const unsigned short* __restrict__ g0, const unsigned short* __restrict__ g1,
    const unsigned short* __restrict__ g2,
    float* __restrict__ out, long long E)
{
    const long long t = (long long)blockIdx.x * 256 + threadIdx.x;
    const long long pr = t >> 4;       // edge-pair id
    const int sub = (int)t & 15;       // 4-col group within row
    const long long eA = pr * 2;
    if (eA >= E) return;
    const long long eB = (eA + 1 < E) ? eA + 1 : eA;

    // issue all index loads
    const long long a0 = i0[eA], a1 = i1[eA], a2 = i2[eA];
    const long long b0 = i0[eB], b1 = i1[eB], b2 = i2[eB];

    // issue all gather loads (6 in flight)
    const uint2 va0 = *(const uint2*)(g0 + a0 * OUT_DIM + sub * 4);
    const uint2 va1 = *(const uint2*)(g1 + a1 * OUT_DIM + sub * 4);
    const uint2 va2 = *(const uint2*)(g2 + a2 * OUT_DIM + sub * 4);
    const uint2 vb0 = *(const uint2*)(g0 + b0 * OUT_DIM + sub * 4);
    const uint2 vb1 = *(const uint2*)(g1 + b1 * OUT_DIM + sub * 4);
    const uint2 vb2 = *(const uint2*)(g2 + b2 * OUT_DIM + sub * 4);

    const float4 fa0 = bf4_to_f4(va0), fa1 = bf4_to_f4(va1), fa2 = bf4_to_f4(va2);
    const float4 fb0 = bf4_to_f4(vb0), fb1 = bf4_to_f4(vb1), fb2 = bf4_to_f4(vb2);

    float4 pA, pB;
    pA.x = fa0.x + fa1.x + fa2.x;
    pA.y = fa0.y + fa1.y + fa2.y;
    pA.z = fa0.z + fa1.z + fa2.z;
    pA.w = fa0.w + fa1.w + fa2.w;
    pB.x = fb0.x + fb1.x + fb2.x;
    pB.y = fb0.y + fb1.y + fb2.y;
    pB.z = fb0.z + fb1.z + fb2.z;
    pB.w = fb0.w + fb1.w + fb2.w;
    pA.x = pA.x >= 0.f ? pA.x : ALPHA * pA.x;
    pA.y = pA.y >= 0.f ? pA.y : ALPHA * pA.y;
    pA.z = pA.z >= 0.f ? pA.z : ALPHA * pA.z;
    pA.w = pA.w >= 0.f ? pA.w : ALPHA * pA.w;
    pB.x = pB.x >= 0.f ? pB.x : ALPHA * pB.x;
    pB.y = pB.y >= 0.f ? pB.y : ALPHA * pB.y;
    pB.z = pB.z >= 0.f ? pB.z : ALPHA * pB.z;
    pB.w = pB.w >= 0.f ? pB.w : ALPHA * pB.w;

    *(float4*)(out + eA * OUT_DIM + sub * 4) = pA;
    if (eB != eA)
        *(float4*)(out + eB * OUT_DIM + sub * 4) = pB;
}

// ---------------------------------------------------------------------------
// Fallback (only if ws too small for tables): direct per-edge compute.
// ---------------------------------------------------------------------------
__global__ __launch_bounds__(256) void fused_fallback_kernel(
    const float* __restrict__ T, const float* __restrict__ Pp,
    const int* __restrict__ i0, const int* __restrict__ i1, const int* __restrict__ i2,
    const float* __restrict__ M, float* __restrict__ out, long long E)
{
    const int wave = threadIdx.x >> 6;
    const int lane = threadIdx.x & 63;
    const long long wavesTotal = (long long)gridDim.x * 4;
    const float* __restrict__ M0 = M;
    const float* __restrict__ M1 = M + IN_DIM * OUT_DIM;
    const float* __restrict__ M2 = M + 2 * IN_DIM * OUT_DIM;
    for (long long e = (long long)blockIdx.x * 4 + wave; e < E; e += wavesTotal) {
        const float* __restrict__ x0 = T + (long long)i0[e] * IN_DIM;
        const float* __restrict__ x1 = T + (long long)i1[e] * IN_DIM;
        const float* __restrict__ x2 = Pp + (long long)i2[e] * IN_DIM;
        float acc = 0.f;
#pragma unroll 4
        for (int k = 0; k < IN_DIM; ++k) {
            acc = fmaf(x0[k], M0[k * OUT_DIM + lane], acc);
            acc = fmaf(x1[k], M1[k * OUT_DIM + lane], acc);
            acc = fmaf(x2[k], M2[k * OUT_DIM + lane], acc);
        }
        acc = acc >= 0.f ? acc : ALPHA * acc;
        out[e * OUT_DIM + lane] = acc;
    }
}

// ---------------------------------------------------------------------------
extern "C" void kernel_launch(void* const* d_in, const int* in_sizes, int n_in,
                              void* d_out, int out_size, void* d_ws, size_t ws_size,
                              hipStream_t stream) {
    const float* T    = (const float*)d_in[0];  // taxPayer_feats [N_C,128]
    const float* Pp   = (const float*)d_in[1];  // person_feats   [N_P,128]
    // d_in[2] item_feats: unused for PCC
    const int*   i0   = (const int*)d_in[3];
    const int*   i1   = (const int*)d_in[4];
    const int*   i2   = (const int*)d_in[5];
    const float* Pc   = (const float*)d_in[6];  // P_company [128,64]
    const float* Pper = (const float*)d_in[7];  // P_person  [128,64]
    const float* W    = (const float*)d_in[9];  // W_PCC     [192,64]
    float* out = (float*)d_out;

    const int n_c = in_sizes[0] / IN_DIM;
    const int n_p = in_sizes[1] / IN_DIM;
    const long long E = in_sizes[3];

    // ws layout: [M f32 3*128*64][Mt bf16 3*64*128][tables bf16]
    float* M = (float*)d_ws;
    unsigned short* Mt = (unsigned short*)((char*)d_ws + 98304);
    const size_t tblOff = 98304 + 49152;  // 147456, 16B aligned
    const size_t tblBytes = ((size_t)n_c * 2 + (size_t)n_p) * OUT_DIM * sizeof(unsigned short);

    // 1) fused projection matrices (f32 + transposed bf16)
    compute_M_kernel<<<48, 256, 0, stream>>>(Pc, Pper, W, M, Mt);

    if (ws_size >= tblOff + tblBytes) {
        unsigned short* g0 = (unsigned short*)((char*)d_ws + tblOff);  // [n_c][64]
        unsigned short* g1 = g0 + (size_t)n_c * OUT_DIM;               // [n_c][64]
        unsigned short* g2 = g1 + (size_t)n_c * OUT_DIM;               // [n_p][64]

        // 2) tables via MFMA: g0/g1 from taxPayer (one read of T), g2 from person
        table_mfma_kernel<2><<<512, 256, 0, stream>>>(T, n_c, Mt, g0);
        table_mfma_kernel<1><<<512, 256, 0, stream>>>(
            Pp, n_p, Mt + (size_t)2 * OUT_DIM * IN_DIM, g2);

        // 3) gather + add + LeakyReLU (2 edges per thread)
        const long long pairs = (E + 1) / 2;
        const long long threads = pairs * 16;
        gather_kernel<<<(int)((threads + 255) / 256), 256, 0, stream>>>(
            i0, i1, i2, g0, g1, g2, out, E);
    } else {
        fused_fallback_kernel<<<16384, 256, 0, stream>>>(T, Pp, i0, i1, i2, M, out, E);
    }
}

// Round 5
// 190.790 us; speedup vs baseline: 3.1521x; 1.0107x over previous
//
#include <hip/hip_runtime.h>

#define IN_DIM 128
#define OUT_DIM 64
#define ALPHA 0.2f

typedef __attribute__((ext_vector_type(8))) short short8v;  // 8 bf16 (4 VGPRs)
typedef __attribute__((ext_vector_type(4))) float f32x4;    // MFMA acc

__device__ __forceinline__ unsigned short bf16rne(float x) {
    union { float f; unsigned u; } c; c.f = x;
    const unsigned u = c.u;
    return (unsigned short)((u + 0x7fffu + ((u >> 16) & 1u)) >> 16);
}

// ---------------------------------------------------------------------------
// Kernel 1: M_b = P_b @ W_slice_b -> f32 M[3][128][64] and bf16 Mt[3][64][128]
// ---------------------------------------------------------------------------
__global__ __launch_bounds__(256) void compute_M_kernel(
    const float* __restrict__ P_company,
    const float* __restrict__ P_person,
    const float* __restrict__ W_PCC,
    float* __restrict__ M,              // [3][128][64] f32 (fallback path)
    unsigned short* __restrict__ Mt)    // [3][64][128] bf16 (transposed)
{
    const int mb = blockIdx.x >> 4;     // which matrix (0,1,2)
    const int chunk = blockIdx.x & 15;
    const float* __restrict__ P = (mb == 2) ? P_person : P_company;
    const float* __restrict__ Wb = W_PCC + mb * OUT_DIM * OUT_DIM;
    float* __restrict__ Mb = M + mb * IN_DIM * OUT_DIM;
    const int base = chunk * 512;
    for (int idx = base + threadIdx.x; idx < base + 512; idx += 256) {
        const int r = idx >> 6;   // k index 0..127
        const int c = idx & 63;   // col 0..63
        float acc = 0.f;
#pragma unroll
        for (int k = 0; k < OUT_DIM; ++k)
            acc = fmaf(P[r * OUT_DIM + k], Wb[k * OUT_DIM + c], acc);
        Mb[idx] = acc;
        Mt[(mb * OUT_DIM + c) * IN_DIM + r] = bf16rne(acc);
    }
}

// ---------------------------------------------------------------------------
// Kernel 2: table GEMM via MFMA, merged dispatch.
// Each wave computes ONE table's 64 cols for a 16-row tile; B (one matrix,
// bf16) lives in 64 VGPRs, preloaded once per wave. A (f32) is double-buffered
// in registers: next tile's 8 float4 loads issue before this tile's MFMAs.
// taxPayer blocks: waves {0,1} share tile (table 0/1), waves {2,3} next tile
// -> A cache lines fetched once from HBM, dup wave read hits L2.
// Fragment maps (16x16x32 bf16):
//   a[4h+j] = A[l&15][k0 + 16h + (l>>4)*4 + j]
//   b[4h+j] = M[k0 + 16h + (l>>4)*4 + j][c0 + (l&15)]
//   D[(l>>4)*4 + j][c0 + (l&15)] = acc[j]
// ---------------------------------------------------------------------------
union F4 { float4 v; float f[4]; };

__device__ __forceinline__ void load_A(F4* L, const float* __restrict__ feats,
                                       int nrows, int tile, int fr, int fq) {
    long long ar = (long long)tile * 16 + fr;
    if (ar >= nrows) ar = nrows - 1;
    const float* __restrict__ A = feats + ar * IN_DIM;
#pragma unroll
    for (int k0i = 0; k0i < 4; ++k0i) {
        L[k0i * 2 + 0].v = *(const float4*)(A + k0i * 32 + fq * 4);
        L[k0i * 2 + 1].v = *(const float4*)(A + k0i * 32 + 16 + fq * 4);
    }
}

__device__ __forceinline__ void table_body(
    const float* __restrict__ feats, int nrows,
    const unsigned short* __restrict__ Mtb,  // one matrix [64][128] bf16
    unsigned short* __restrict__ out,        // one table [nrows][64] bf16
    int tile0, int tstride)
{
    const int lane = threadIdx.x & 63;
    const int fr   = lane & 15;   // A-row / B,D-col index
    const int fq   = lane >> 4;   // k-subgroup / D-row-group

    // preload B fragments: 4(k0) x 4(c0) x 8 bf16 = 64 VGPRs
    union FragU { short8v v; uint2 q[2]; };
    short8v bfrag[4][4];
#pragma unroll
    for (int k0i = 0; k0i < 4; ++k0i)
#pragma unroll
        for (int c0i = 0; c0i < 4; ++c0i) {
            const unsigned short* p =
                Mtb + ((size_t)(c0i * 16 + fr)) * IN_DIM + k0i * 32 + fq * 4;
            FragU f;
            f.q[0] = *(const uint2*)(p);
            f.q[1] = *(const uint2*)(p + 16);
            bfrag[k0i][c0i] = f.v;
        }

    const int ntiles = (nrows + 15) >> 4;
    union AF { short8v v; unsigned short u[8]; };

    int tile = tile0;
    if (tile >= ntiles) return;
    F4 La[8];
    load_A(La, feats, nrows, tile, fr, fq);

    for (; tile < ntiles; tile += tstride) {
        const int next = tile + tstride;
        F4 Lb[8];
        if (next < ntiles) load_A(Lb, feats, nrows, next, fr, fq);  // prefetch

        short8v afrag[4];
#pragma unroll
        for (int k0i = 0; k0i < 4; ++k0i) {
            AF af;
#pragma unroll
            for (int j = 0; j < 4; ++j) {
                af.u[j]     = bf16rne(La[k0i * 2 + 0].f[j]);
                af.u[4 + j] = bf16rne(La[k0i * 2 + 1].f[j]);
            }
            afrag[k0i] = af.v;
        }

        f32x4 acc[4];
#pragma unroll
        for (int c0i = 0; c0i < 4; ++c0i) acc[c0i] = (f32x4){0.f, 0.f, 0.f, 0.f};
#pragma unroll
        for (int k0i = 0; k0i < 4; ++k0i)
#pragma unroll
            for (int c0i = 0; c0i < 4; ++c0i)
                acc[c0i] = __builtin_amdgcn_mfma_f32_16x16x32_bf16(
                    afrag[k0i], bfrag[k0i][c0i], acc[c0i], 0, 0, 0);

        const long long row0 = (long long)tile * 16;
#pragma unroll
        for (int c0i = 0; c0i < 4; ++c0i)
#pragma unroll
            for (int j = 0; j < 4; ++j) {
                const long long rg = row0 + fq * 4 + j;
                if (rg < nrows)
                    out[rg * OUT_DIM + c0i * 16 + fr] = bf16rne(acc[c0i][j]);
            }

#pragma unroll
        for (int i = 0; i < 8; ++i) La[i] = Lb[i];
    }
}

__global__ __launch_bounds__(256) void tables_kernel(
    const float* __restrict__ T, int n_c,
    const float* __restrict__ Pp, int n_p,
    const unsigned short* __restrict__ Mt,   // [3][64][128]
    unsigned short* __restrict__ g0,         // [2][n_c][64] (g0 then g1)
    unsigned short* __restrict__ g2,         // [n_p][64]
    int gsplit)
{
    const int w = threadIdx.x >> 6;
    if ((int)blockIdx.x < gsplit) {
        // taxPayer: waves {0,1} -> tile 2*bid, tables {0,1}; waves {2,3} -> tile 2*bid+1
        const int table = w & 1;
        const int tile0 = (int)blockIdx.x * 2 + (w >> 1);
        table_body(T, n_c,
                   Mt + (size_t)table * OUT_DIM * IN_DIM,
                   g0 + (size_t)table * n_c * OUT_DIM,
                   tile0, gsplit * 2);
    } else {
        const int bid = (int)blockIdx.x - gsplit;
        const int nb  = (int)gridDim.x - gsplit;
        table_body(Pp, n_p,
                   Mt + (size_t)2 * OUT_DIM * IN_DIM,
                   g2, bid * 4 + w, nb * 4);
    }
}

// ---------------------------------------------------------------------------
// Kernel 3: gather + add + LeakyReLU.  Tables bf16 [nrows][64].
// 8 lanes/edge (lane loads uint4 = 8 bf16 = 16B; 8x16B = full 128B row),
// 4 edges/thread: 12 idx loads then 12 gathers in flight before any use.
// Output: 2 float4 per edge per lane (stride-32B halves; L2 merges).
// ---------------------------------------------------------------------------
__global__ __launch_bounds__(256) void gather_kernel(
    const int* __restrict__ i0, const int* __restrict__ i1, const int* __restrict__ i2,
    const unsigned short* __restrict__ g0, const unsigned short* __restrict__ g1,
    const unsigned short* __restrict__ g2,
    float* __restrict__ out, long long E)
{
    const long long t = (long long)blockIdx.x * 256 + threadIdx.x;
    const long long grp = t >> 3;      // 8 lanes per group
    const int j = (int)t & 7;          // 8-col sub-block within row
    const long long e0 = grp * 4;
    if (e0 >= E) return;

    long long e[4];
    bool live[4];
#pragma unroll
    for (int k = 0; k < 4; ++k) {
        e[k] = e0 + k;
        live[k] = e[k] < E;
        if (!live[k]) e[k] = E - 1;
    }

    int a0[4], a1[4], a2[4];
#pragma unroll
    for (int k = 0; k < 4; ++k) {
        a0[k] = i0[e[k]];
        a1[k] = i1[e[k]];
        a2[k] = i2[e[k]];
    }

    uint4 v0[4], v1[4], v2[4];
#pragma unroll
    for (int k = 0; k < 4; ++k) {
        v0[k] = *(const uint4*)(g0 + (long long)a0[k] * OUT_DIM + j * 8);
        v1[k] = *(const uint4*)(g1 + (long long)a1[k] * OUT_DIM + j * 8);
        v2[k] = *(const uint4*)(g2 + (long long)a2[k] * OUT_DIM + j * 8);
    }

#pragma unroll
    for (int k = 0; k < 4; ++k) {
        const unsigned u0[4] = {v0[k].x, v0[k].y, v0[k].z, v0[k].w};
        const unsigned u1[4] = {v1[k].x, v1[k].y, v1[k].z, v1[k].w};
        const unsigned u2[4] = {v2[k].x, v2[k].y, v2[k].z, v2[k].w};
        float s[8];
#pragma unroll
        for (int m = 0; m < 4; ++m) {
            const float lo = __uint_as_float(u0[m] << 16)
                           + __uint_as_float(u1[m] << 16)
                           + __uint_as_float(u2[m] << 16);
            const float hi = __uint_as_float(u0[m] & 0xffff0000u)
                           + __uint_as_float(u1[m] & 0xffff0000u)
                           + __uint_as_float(u2[m] & 0xffff0000u);
            s[2 * m]     = lo >= 0.f ? lo : ALPHA * lo;
            s[2 * m + 1] = hi >= 0.f ? hi : ALPHA * hi;
        }
        if (live[k]) {
            float* __restrict__ o = out + e[k] * OUT_DIM + j * 8;
            *(float4*)(o)     = make_float4(s[0], s[1], s[2], s[3]);
            *(float4*)(o + 4) = make_float4(s[4], s[5], s[6], s[7]);
        }
    }
}

// ---------------------------------------------------------------------------
// Fallback (only if ws too small for tables): direct per-edge compute.
// ---------------------------------------------------------------------------
__global__ __launch_bounds__(256) void fused_fallback_kernel(
    const float* __restrict__ T, const float* __restrict__ Pp,
    const int* __restrict__ i0, const int* __restrict__ i1, const int* __restrict__ i2,
    const float* __restrict__ M, float* __restrict__ out, long long E)
{
    const int wave = threadIdx.x >> 6;
    const int lane = threadIdx.x & 63;
    const long long wavesTotal = (long long)gridDim.x * 4;
    const float* __restrict__ M0 = M;
    const float* __restrict__ M1 = M + IN_DIM * OUT_DIM;
    const float* __restrict__ M2 = M + 2 * IN_DIM * OUT_DIM;
    for (long long e = (long long)blockIdx.x * 4 + wave; e < E; e += wavesTotal) {
        const float* __restrict__ x0 = T + (long long)i0[e] * IN_DIM;
        const float* __restrict__ x1 = T + (long long)i1[e] * IN_DIM;
        const float* __restrict__ x2 = Pp + (long long)i2[e] * IN_DIM;
        float acc = 0.f;
#pragma unroll 4
        for (int k = 0; k < IN_DIM; ++k) {
            acc = fmaf(x0[k], M0[k * OUT_DIM + lane], acc);
            acc = fmaf(x1[k], M1[k * OUT_DIM + lane], acc);
            acc = fmaf(x2[k], M2[k * OUT_DIM + lane], acc);
        }
        acc = acc >= 0.f ? acc : ALPHA * acc;
        out[e * OUT_DIM + lane] = acc;
    }
}

// ---------------------------------------------------------------------------
extern "C" void kernel_launch(void* const* d_in, const int* in_sizes, int n_in,
                              void* d_out, int out_size, void* d_ws, size_t ws_size,
                              hipStream_t stream) {
    const float* T    = (const float*)d_in[0];  // taxPayer_feats [N_C,128]
    const float* Pp   = (const float*)d_in[1];  // person_feats   [N_P,128]
    // d_in[2] item_feats: unused for PCC
    const int*   i0   = (const int*)d_in[3];
    const int*   i1   = (const int*)d_in[4];
    const int*   i2   = (const int*)d_in[5];
    const float* Pc   = (const float*)d_in[6];  // P_company [128,64]
    const float* Pper = (const float*)d_in[7];  // P_person  [128,64]
    const float* W    = (const float*)d_in[9];  // W_PCC     [192,64]
    float* out = (float*)d_out;

    const int n_c = in_sizes[0] / IN_DIM;
    const int n_p = in_sizes[1] / IN_DIM;
    const long long E = in_sizes[3];

    // ws layout: [M f32 3*128*64][Mt bf16 3*64*128][tables bf16]
    float* M = (float*)d_ws;
    unsigned short* Mt = (unsigned short*)((char*)d_ws + 98304);
    const size_t tblOff = 98304 + 49152;  // 147456, 16B aligned
    const size_t tblBytes = ((size_t)n_c * 2 + (size_t)n_p) * OUT_DIM * sizeof(unsigned short);

    // 1) fused projection matrices (f32 + transposed bf16)
    compute_M_kernel<<<48, 256, 0, stream>>>(Pc, Pper, W, M, Mt);

    if (ws_size >= tblOff + tblBytes) {
        unsigned short* g0 = (unsigned short*)((char*)d_ws + tblOff);  // [n_c][64]
        unsigned short* g1 = g0 + (size_t)n_c * OUT_DIM;               // [n_c][64]
        unsigned short* g2 = g1 + (size_t)n_c * OUT_DIM;               // [n_p][64]

        // 2) both table GEMMs in one dispatch (overlapped streams)
        const int GA = 1024;  // taxPayer blocks (2 tiles x 2 tables per block)
        const int GB = 512;   // person blocks   (4 tiles per block)
        tables_kernel<<<GA + GB, 256, 0, stream>>>(T, n_c, Pp, n_p, Mt, g0, g2, GA);

        // 3) gather + add + LeakyReLU (8 lanes/edge, 4 edges/thread)
        const long long groups = (E + 3) / 4;
        const long long threads = groups * 8;
        gather_kernel<<<(int)((threads + 255) / 256), 256, 0, stream>>>(
            i0, i1, i2, g0, g1, g2, out, E);
    } else {
        fused_fallback_kernel<<<16384, 256, 0, stream>>>(T, Pp, i0, i1, i2, M, out, E);
    }
}